// Round 1
// baseline (583.111 us; speedup 1.0000x reference)
//
#include <hip/hip_runtime.h>

#define N_NODES 50000
#define N_EDGES 800000
#define ETOT    (2 * N_EDGES + N_NODES)   // 1,650,000
#define F       64
#define NEG_SLOPE 0.2f

// monotone float->uint map for atomicMax over floats (exact)
__device__ __forceinline__ unsigned int fmap(float f) {
    unsigned int b = __float_as_uint(f);
    return (b & 0x80000000u) ? ~b : (b | 0x80000000u);
}
__device__ __forceinline__ float funmap(unsigned int u) {
    unsigned int b = (u & 0x80000000u) ? (u & 0x7FFFFFFFu) : ~u;
    return __uint_as_float(b);
}

// xt = x @ W ; s = xt . a[:64] ; d = xt . a[64:128]
__global__ void k_xt(const float* __restrict__ x, const float* __restrict__ W,
                     const float* __restrict__ a, float* __restrict__ xt,
                     float* __restrict__ s_node, float* __restrict__ d_node) {
    __shared__ float Wl[64 * 64];
    __shared__ float xs[4][64];
    const int tid = threadIdx.x;
    for (int i = tid; i < 64 * 64; i += 256) Wl[i] = W[i];
    const int wid  = tid >> 6;
    const int lane = tid & 63;
    const int node = blockIdx.x * 4 + wid;
    if (node < N_NODES) xs[wid][lane] = x[node * F + lane];
    __syncthreads();
    if (node >= N_NODES) return;
    float acc = 0.f;
#pragma unroll
    for (int k = 0; k < 64; ++k) acc += xs[wid][k] * Wl[k * 64 + lane];
    xt[node * F + lane] = acc;
    float ps = acc * a[lane];
    float pd = acc * a[64 + lane];
#pragma unroll
    for (int off = 32; off >= 1; off >>= 1) {
        ps += __shfl_xor(ps, off);
        pd += __shfl_xor(pd, off);
    }
    if (lane == 0) { s_node[node] = ps; d_node[node] = pd; }
}

// e_contrib = edge_attr @ a[128:144]
__global__ void k_edge(const float* __restrict__ ea, const float* __restrict__ a,
                       float* __restrict__ ec) {
    const int e = blockIdx.x * blockDim.x + threadIdx.x;
    if (e >= N_EDGES) return;
    const float4* p = (const float4*)(ea + (size_t)e * 16);
    float acc = 0.f;
#pragma unroll
    for (int i = 0; i < 4; ++i) {
        float4 v = p[i];
        acc += v.x * a[128 + i * 4 + 0] + v.y * a[128 + i * 4 + 1] +
               v.z * a[128 + i * 4 + 2] + v.w * a[128 + i * 4 + 3];
    }
    ec[e] = acc;
}

__device__ __forceinline__ void edge_pair(int t, const int* __restrict__ srcs,
                                          const int* __restrict__ dsts,
                                          int& src, int& dst) {
    if (t < N_EDGES)            { src = srcs[t];            dst = dsts[t]; }
    else if (t < 2 * N_EDGES)   { src = dsts[t - N_EDGES];  dst = srcs[t - N_EDGES]; }
    else                        { src = t - 2 * N_EDGES;    dst = src; }
}

// logits + segment max
__global__ void k_logit(const int* __restrict__ srcs, const int* __restrict__ dsts,
                        const float* __restrict__ s_node, const float* __restrict__ d_node,
                        const float* __restrict__ ec, float* __restrict__ logit,
                        unsigned int* __restrict__ mmax) {
    const int t = blockIdx.x * blockDim.x + threadIdx.x;
    if (t >= ETOT) return;
    int src, dst;
    edge_pair(t, srcs, dsts, src, dst);
    float e = 0.f;
    if (t < N_EDGES)          e = ec[t];
    else if (t < 2 * N_EDGES) e = ec[t - N_EDGES];
    float v = s_node[src] + d_node[dst] + e;
    v = (v > 0.f) ? v : NEG_SLOPE * v;   // leaky_relu, T=1
    logit[t] = v;
    atomicMax(&mmax[dst], fmap(v));
}

// z = exp(logit - m[dst]); denom[dst] += z
__global__ void k_z(const int* __restrict__ srcs, const int* __restrict__ dsts,
                    const float* __restrict__ logit, const unsigned int* __restrict__ mmax,
                    float* __restrict__ z, float* __restrict__ denom) {
    const int t = blockIdx.x * blockDim.x + threadIdx.x;
    if (t >= ETOT) return;
    int src, dst;
    edge_pair(t, srcs, dsts, src, dst);
    float m = funmap(mmax[dst]);
    float zz = __expf(logit[t] - m);
    z[t] = zz;
    atomicAdd(&denom[dst], zz);
}

// out[dst] += (z/denom[dst]) * xt[src]   (wave per edge, lane = feature)
__global__ void k_out(const int* __restrict__ srcs, const int* __restrict__ dsts,
                      const float* __restrict__ z, const float* __restrict__ denom,
                      const float* __restrict__ xt, float* __restrict__ out) {
    const int t    = (blockIdx.x * blockDim.x + threadIdx.x) >> 6;
    const int lane = threadIdx.x & 63;
    if (t >= ETOT) return;
    int src, dst;
    edge_pair(t, srcs, dsts, src, dst);
    const float att = z[t] / denom[dst];
    const float val = att * xt[(size_t)src * F + lane];
    atomicAdd(&out[(size_t)dst * F + lane], val);
}

extern "C" void kernel_launch(void* const* d_in, const int* in_sizes, int n_in,
                              void* d_out, int out_size, void* d_ws, size_t ws_size,
                              hipStream_t stream) {
    const float* x    = (const float*)d_in[0];
    const int*   ei   = (const int*)d_in[1];
    const float* ea   = (const float*)d_in[2];
    const float* W    = (const float*)d_in[4];
    const float* a    = (const float*)d_in[5];
    float* out = (float*)d_out;

    const int* srcs = ei;             // edge_index[0]
    const int* dsts = ei + N_EDGES;   // edge_index[1]

    char* ws = (char*)d_ws;
    size_t off = 0;
    auto alloc = [&](size_t bytes) { void* p = ws + off; off = (off + bytes + 255) & ~(size_t)255; return p; };
    float*        xt     = (float*)alloc((size_t)N_NODES * F * 4);
    float*        s_node = (float*)alloc((size_t)N_NODES * 4);
    float*        d_node = (float*)alloc((size_t)N_NODES * 4);
    float*        ec     = (float*)alloc((size_t)N_EDGES * 4);
    unsigned int* mmax   = (unsigned int*)alloc((size_t)N_NODES * 4);
    float*        denom  = (float*)alloc((size_t)N_NODES * 4);
    float*        logit  = (float*)alloc((size_t)ETOT * 4);
    float*        z      = (float*)alloc((size_t)ETOT * 4);

    hipMemsetAsync(out,   0, (size_t)N_NODES * F * 4, stream);
    hipMemsetAsync(mmax,  0, (size_t)N_NODES * 4, stream);  // fmap-domain minimum
    hipMemsetAsync(denom, 0, (size_t)N_NODES * 4, stream);

    k_xt<<<(N_NODES + 3) / 4, 256, 0, stream>>>(x, W, a, xt, s_node, d_node);
    k_edge<<<(N_EDGES + 255) / 256, 256, 0, stream>>>(ea, a, ec);
    k_logit<<<(ETOT + 255) / 256, 256, 0, stream>>>(srcs, dsts, s_node, d_node, ec, logit, mmax);
    k_z<<<(ETOT + 255) / 256, 256, 0, stream>>>(srcs, dsts, logit, mmax, z, denom);
    k_out<<<((ETOT * 64) + 255) / 256, 256, 0, stream>>>(srcs, dsts, z, denom, xt, out);
}

// Round 2
// 381.947 us; speedup vs baseline: 1.5267x; 1.5267x over previous
//
#include <hip/hip_runtime.h>

#define N_NODES 50000
#define N_EDGES 800000
#define ETOT    (2 * N_EDGES + N_NODES)   // 1,650,000
#define F       64
#define NEG_SLOPE 0.2f
#define SCAN_B  1024
#define NB      ((N_NODES + SCAN_B - 1) / SCAN_B)   // 49 (<= 64)

// ---------------- xt = x @ W ; s = xt.a[:64] ; d = xt.a[64:128] ----------------
__global__ void k_xt(const float* __restrict__ x, const float* __restrict__ W,
                     const float* __restrict__ a, float* __restrict__ xt,
                     float* __restrict__ s_node, float* __restrict__ d_node) {
    __shared__ float Wl[64 * 64];
    __shared__ float xs[4][64];
    const int tid = threadIdx.x;
    for (int i = tid; i < 64 * 64; i += 256) Wl[i] = W[i];
    const int wid  = tid >> 6;
    const int lane = tid & 63;
    const int node = blockIdx.x * 4 + wid;
    if (node < N_NODES) xs[wid][lane] = x[node * F + lane];
    __syncthreads();
    if (node >= N_NODES) return;
    float acc = 0.f;
#pragma unroll
    for (int k = 0; k < 64; ++k) acc += xs[wid][k] * Wl[k * 64 + lane];
    xt[node * F + lane] = acc;
    float ps = acc * a[lane];
    float pd = acc * a[64 + lane];
#pragma unroll
    for (int off = 32; off >= 1; off >>= 1) {
        ps += __shfl_xor(ps, off);
        pd += __shfl_xor(pd, off);
    }
    if (lane == 0) { s_node[node] = ps; d_node[node] = pd; }
}

// ---------------- e_contrib = edge_attr @ a[128:144] ----------------
__global__ void k_edge(const float* __restrict__ ea, const float* __restrict__ a,
                       float* __restrict__ ec) {
    const int e = blockIdx.x * blockDim.x + threadIdx.x;
    if (e >= N_EDGES) return;
    const float4* p = (const float4*)(ea + (size_t)e * 16);
    float acc = 0.f;
#pragma unroll
    for (int i = 0; i < 4; ++i) {
        float4 v = p[i];
        acc += v.x * a[128 + i * 4 + 0] + v.y * a[128 + i * 4 + 1] +
               v.z * a[128 + i * 4 + 2] + v.w * a[128 + i * 4 + 3];
    }
    ec[e] = acc;
}

__device__ __forceinline__ void edge_pair(int t, const int* __restrict__ srcs,
                                          const int* __restrict__ dsts,
                                          int& src, int& dst) {
    if (t < N_EDGES)            { src = srcs[t];            dst = dsts[t]; }
    else if (t < 2 * N_EDGES)   { src = dsts[t - N_EDGES];  dst = srcs[t - N_EDGES]; }
    else                        { src = t - 2 * N_EDGES;    dst = src; }
}

// ---------------- in-degree histogram (forward+backward edges; self-loop added in scan) ----
__global__ void k_hist(const int* __restrict__ srcs, const int* __restrict__ dsts,
                       int* __restrict__ deg) {
    const int t = blockIdx.x * blockDim.x + threadIdx.x;
    if (t < N_EDGES)            atomicAdd(&deg[dsts[t]], 1);
    else if (t < 2 * N_EDGES)   atomicAdd(&deg[srcs[t - N_EDGES]], 1);
}

// ---------------- exclusive scan, 2-level ----------------
__global__ void k_scanA(const int* __restrict__ deg, int* __restrict__ part,
                        int* __restrict__ bsum) {
    __shared__ int wtot[16];
    __shared__ int wexc[16];
    const int tid = threadIdx.x, lane = tid & 63, wid = tid >> 6;
    const int i = blockIdx.x * SCAN_B + tid;
    const int v = (i < N_NODES) ? (deg[i] + 1) : 0;   // +1 = self-loop
    int s = v;
#pragma unroll
    for (int off = 1; off < 64; off <<= 1) { int u = __shfl_up(s, off); if (lane >= off) s += u; }
    if (lane == 63) wtot[wid] = s;
    __syncthreads();
    if (tid == 0) { int run = 0; for (int w = 0; w < 16; ++w) { wexc[w] = run; run += wtot[w]; } bsum[blockIdx.x] = run; }
    __syncthreads();
    if (i < N_NODES) part[i] = wexc[wid] + s - v;
}

__global__ void k_scanB(int* __restrict__ bsum) {   // exclusive scan of NB<=64 values, 1 wave
    const int lane = threadIdx.x;
    const int v = (lane < NB) ? bsum[lane] : 0;
    int s = v;
#pragma unroll
    for (int off = 1; off < 64; off <<= 1) { int u = __shfl_up(s, off); if (lane >= off) s += u; }
    if (lane < NB) bsum[lane] = s - v;
}

__global__ void k_scanC(const int* __restrict__ part, const int* __restrict__ bsum,
                        int* __restrict__ offs, int* __restrict__ cursor) {
    const int i = blockIdx.x * SCAN_B + threadIdx.x;
    if (i < N_NODES) { const int o = part[i] + bsum[blockIdx.x]; offs[i] = o; cursor[i] = o; }
    if (i == 0) offs[N_NODES] = ETOT;
}

// ---------------- scatter edges into CSR, materializing logits ----------------
__global__ void k_scatter(const int* __restrict__ srcs, const int* __restrict__ dsts,
                          const float* __restrict__ s_node, const float* __restrict__ d_node,
                          const float* __restrict__ ec, int* __restrict__ cursor,
                          int* __restrict__ csr_src, float* __restrict__ csr_logit) {
    const int t = blockIdx.x * blockDim.x + threadIdx.x;
    if (t >= ETOT) return;
    int src, dst;
    edge_pair(t, srcs, dsts, src, dst);
    float e = 0.f;
    if (t < N_EDGES)          e = ec[t];
    else if (t < 2 * N_EDGES) e = ec[t - N_EDGES];
    float v = s_node[src] + d_node[dst] + e;
    v = (v > 0.f) ? v : NEG_SLOPE * v;   // leaky_relu, T=1
    const int pos = atomicAdd(&cursor[dst], 1);
    csr_src[pos]   = src;
    csr_logit[pos] = v;
}

// ---------------- wave-per-node: softmax + weighted feature gather ----------------
__global__ void k_node(const int* __restrict__ offs, const int* __restrict__ csr_src,
                       const float* __restrict__ csr_logit, const float* __restrict__ xt,
                       float* __restrict__ out) {
    const int node = (blockIdx.x * blockDim.x + threadIdx.x) >> 6;
    const int lane = threadIdx.x & 63;
    if (node >= N_NODES) return;
    const int beg = offs[node], end = offs[node + 1];
    // phase 1: max
    float m = -1e30f;
    for (int j = beg + lane; j < end; j += 64) m = fmaxf(m, csr_logit[j]);
#pragma unroll
    for (int off = 32; off >= 1; off >>= 1) m = fmaxf(m, __shfl_xor(m, off));
    // phase 2: sum exp
    float sum = 0.f;
    for (int j = beg + lane; j < end; j += 64) sum += __expf(csr_logit[j] - m);
#pragma unroll
    for (int off = 32; off >= 1; off >>= 1) sum += __shfl_xor(sum, off);
    const float inv = 1.0f / sum;
    // phase 3: out[node][lane] = sum_j att_j * xt[src_j][lane]
    float acc = 0.f;
    for (int j = beg; j < end; ++j) {
        const float att = __expf(csr_logit[j] - m) * inv;   // broadcast loads
        acc += att * xt[(size_t)csr_src[j] * F + lane];
    }
    out[(size_t)node * F + lane] = acc;
}

extern "C" void kernel_launch(void* const* d_in, const int* in_sizes, int n_in,
                              void* d_out, int out_size, void* d_ws, size_t ws_size,
                              hipStream_t stream) {
    const float* x    = (const float*)d_in[0];
    const int*   ei   = (const int*)d_in[1];
    const float* ea   = (const float*)d_in[2];
    const float* W    = (const float*)d_in[4];
    const float* a    = (const float*)d_in[5];
    float* out = (float*)d_out;

    const int* srcs = ei;             // edge_index[0]
    const int* dsts = ei + N_EDGES;   // edge_index[1]

    char* ws = (char*)d_ws;
    size_t off = 0;
    auto alloc = [&](size_t bytes) { void* p = ws + off; off = (off + bytes + 255) & ~(size_t)255; return p; };
    float* xt        = (float*)alloc((size_t)N_NODES * F * 4);
    float* s_node    = (float*)alloc((size_t)N_NODES * 4);
    float* d_node    = (float*)alloc((size_t)N_NODES * 4);
    float* ec        = (float*)alloc((size_t)N_EDGES * 4);
    int*   deg       = (int*)alloc((size_t)N_NODES * 4);
    int*   part      = (int*)alloc((size_t)N_NODES * 4);
    int*   bsum      = (int*)alloc((size_t)NB * 4);
    int*   offs      = (int*)alloc((size_t)(N_NODES + 1) * 4);
    int*   cursor    = (int*)alloc((size_t)N_NODES * 4);
    int*   csr_src   = (int*)alloc((size_t)ETOT * 4);
    float* csr_logit = (float*)alloc((size_t)ETOT * 4);

    hipMemsetAsync(deg, 0, (size_t)N_NODES * 4, stream);

    k_xt<<<(N_NODES + 3) / 4, 256, 0, stream>>>(x, W, a, xt, s_node, d_node);
    k_edge<<<(N_EDGES + 255) / 256, 256, 0, stream>>>(ea, a, ec);
    k_hist<<<(2 * N_EDGES + 255) / 256, 256, 0, stream>>>(srcs, dsts, deg);
    k_scanA<<<NB, SCAN_B, 0, stream>>>(deg, part, bsum);
    k_scanB<<<1, 64, 0, stream>>>(bsum);
    k_scanC<<<NB, SCAN_B, 0, stream>>>(part, bsum, offs, cursor);
    k_scatter<<<(ETOT + 255) / 256, 256, 0, stream>>>(srcs, dsts, s_node, d_node, ec, cursor, csr_src, csr_logit);
    k_node<<<((size_t)N_NODES * 64 + 255) / 256, 256, 0, stream>>>(offs, csr_src, csr_logit, xt, out);
}

// Round 3
// 263.881 us; speedup vs baseline: 2.2097x; 1.4474x over previous
//
#include <hip/hip_runtime.h>

#define N_NODES 50000
#define N_EDGES 800000
#define ETOT    (2 * N_EDGES + N_NODES)   // 1,650,000
#define F       64
#define NEG_SLOPE 0.2f
#define SCAN_B  1024
#define NB      ((N_NODES + SCAN_B - 1) / SCAN_B)   // 49 (<= 64)

__device__ __forceinline__ float leaky(float v) {
    return (v > 0.f) ? v : NEG_SLOPE * v;
}

// ---------------- xt = x @ W ; sd[n] = {xt.a[:64], xt.a[64:128]} ----------------
__global__ void k_xt(const float* __restrict__ x, const float* __restrict__ W,
                     const float* __restrict__ a, float* __restrict__ xt,
                     float2* __restrict__ sd) {
    __shared__ float Wl[64 * 64];
    __shared__ float xs[4][64];
    const int tid = threadIdx.x;
    for (int i = tid; i < 64 * 64; i += 256) Wl[i] = W[i];
    const int wid  = tid >> 6;
    const int lane = tid & 63;
    const int node = blockIdx.x * 4 + wid;
    if (node < N_NODES) xs[wid][lane] = x[node * F + lane];
    __syncthreads();
    if (node >= N_NODES) return;
    float acc = 0.f;
#pragma unroll
    for (int k = 0; k < 64; ++k) acc += xs[wid][k] * Wl[k * 64 + lane];
    xt[node * F + lane] = acc;
    float ps = acc * a[lane];
    float pd = acc * a[64 + lane];
#pragma unroll
    for (int off = 32; off >= 1; off >>= 1) {
        ps += __shfl_xor(ps, off);
        pd += __shfl_xor(pd, off);
    }
    if (lane == 0) sd[node] = make_float2(ps, pd);
}

// ---------------- in-degree histogram (both directions; self-loop added in scan) ----
__global__ void k_hist(const int* __restrict__ srcs, const int* __restrict__ dsts,
                       int* __restrict__ deg) {
    const int t = blockIdx.x * blockDim.x + threadIdx.x;
    if (t >= N_EDGES) return;
    atomicAdd(&deg[dsts[t]], 1);
    atomicAdd(&deg[srcs[t]], 1);
}

// ---------------- exclusive scan, 2-level ----------------
__global__ void k_scanA(const int* __restrict__ deg, int* __restrict__ part,
                        int* __restrict__ bsum) {
    __shared__ int wtot[16];
    __shared__ int wexc[16];
    const int tid = threadIdx.x, lane = tid & 63, wid = tid >> 6;
    const int i = blockIdx.x * SCAN_B + tid;
    const int v = (i < N_NODES) ? (deg[i] + 1) : 0;   // +1 = self-loop
    int s = v;
#pragma unroll
    for (int off = 1; off < 64; off <<= 1) { int u = __shfl_up(s, off); if (lane >= off) s += u; }
    if (lane == 63) wtot[wid] = s;
    __syncthreads();
    if (tid == 0) { int run = 0; for (int w = 0; w < 16; ++w) { wexc[w] = run; run += wtot[w]; } bsum[blockIdx.x] = run; }
    __syncthreads();
    if (i < N_NODES) part[i] = wexc[wid] + s - v;
}

__global__ void k_scanB(int* __restrict__ bsum) {   // exclusive scan of NB<=64 values, 1 wave
    const int lane = threadIdx.x;
    const int v = (lane < NB) ? bsum[lane] : 0;
    int s = v;
#pragma unroll
    for (int off = 1; off < 64; off <<= 1) { int u = __shfl_up(s, off); if (lane >= off) s += u; }
    if (lane < NB) bsum[lane] = s - v;
}

__global__ void k_scanC(const int* __restrict__ part, const int* __restrict__ bsum,
                        int* __restrict__ offs, int* __restrict__ cursor) {
    const int i = blockIdx.x * SCAN_B + threadIdx.x;
    if (i < N_NODES) { const int o = part[i] + bsum[blockIdx.x]; offs[i] = o; cursor[i] = o; }
    if (i == 0) offs[N_NODES] = ETOT;
}

// ---------------- scatter: one thread per original edge handles both directions ----
__global__ void k_scatter(const int* __restrict__ srcs, const int* __restrict__ dsts,
                          const float2* __restrict__ sd, const float* __restrict__ ea,
                          const float* __restrict__ a, int* __restrict__ cursor,
                          int2* __restrict__ csr) {
    const int t = blockIdx.x * blockDim.x + threadIdx.x;
    if (t < N_EDGES) {
        const int s = srcs[t], d = dsts[t];
        const float4* p = (const float4*)(ea + (size_t)t * 16);
        float e = 0.f;
#pragma unroll
        for (int i = 0; i < 4; ++i) {
            float4 v = p[i];
            e += v.x * a[128 + i * 4 + 0] + v.y * a[128 + i * 4 + 1] +
                 v.z * a[128 + i * 4 + 2] + v.w * a[128 + i * 4 + 3];
        }
        const float2 ss = sd[s], dd = sd[d];
        const float v1 = leaky(ss.x + dd.y + e);   // src=s -> dst=d
        const float v2 = leaky(dd.x + ss.y + e);   // src=d -> dst=s
        const int p1 = atomicAdd(&cursor[d], 1);
        csr[p1] = make_int2(s, __float_as_int(v1));
        const int p2 = atomicAdd(&cursor[s], 1);
        csr[p2] = make_int2(d, __float_as_int(v2));
    } else if (t < N_EDGES + N_NODES) {
        const int n = t - N_EDGES;
        const float2 nn = sd[n];
        const float v = leaky(nn.x + nn.y);
        const int pos = atomicAdd(&cursor[n], 1);
        csr[pos] = make_int2(n, __float_as_int(v));
    }
}

// ---------------- wave-per-node: softmax + weighted feature gather ----------------
__global__ void k_node(const int* __restrict__ offs, const int2* __restrict__ csr,
                       const float* __restrict__ xt, float* __restrict__ out) {
    const int node = (blockIdx.x * blockDim.x + threadIdx.x) >> 6;
    const int lane = threadIdx.x & 63;
    if (node >= N_NODES) return;
    const int beg = offs[node], end = offs[node + 1];
    // phase 1: max
    float m = -1e30f;
    for (int j = beg + lane; j < end; j += 64) m = fmaxf(m, __int_as_float(csr[j].y));
#pragma unroll
    for (int off = 32; off >= 1; off >>= 1) m = fmaxf(m, __shfl_xor(m, off));
    // phase 2: sum exp
    float sum = 0.f;
    for (int j = beg + lane; j < end; j += 64) sum += __expf(__int_as_float(csr[j].y) - m);
#pragma unroll
    for (int off = 32; off >= 1; off >>= 1) sum += __shfl_xor(sum, off);
    const float inv = 1.0f / sum;
    // phase 3: 4-way j-parallel, 16 feature-chunks of float4
    const int jg = lane >> 4;        // 0..3
    const int fc = lane & 15;        // 0..15
    float4 acc = make_float4(0.f, 0.f, 0.f, 0.f);
    for (int j = beg + jg; j < end; j += 4) {
        const int2 ent = csr[j];
        const float att = __expf(__int_as_float(ent.y) - m) * inv;
        const float4 v = *(const float4*)(xt + (size_t)ent.x * F + fc * 4);
        acc.x += att * v.x; acc.y += att * v.y; acc.z += att * v.z; acc.w += att * v.w;
    }
#pragma unroll
    for (int off = 16; off <= 32; off <<= 1) {
        acc.x += __shfl_xor(acc.x, off);
        acc.y += __shfl_xor(acc.y, off);
        acc.z += __shfl_xor(acc.z, off);
        acc.w += __shfl_xor(acc.w, off);
    }
    if (jg == 0) *(float4*)(out + (size_t)node * F + fc * 4) = acc;
}

extern "C" void kernel_launch(void* const* d_in, const int* in_sizes, int n_in,
                              void* d_out, int out_size, void* d_ws, size_t ws_size,
                              hipStream_t stream) {
    const float* x    = (const float*)d_in[0];
    const int*   ei   = (const int*)d_in[1];
    const float* ea   = (const float*)d_in[2];
    const float* W    = (const float*)d_in[4];
    const float* a    = (const float*)d_in[5];
    float* out = (float*)d_out;

    const int* srcs = ei;             // edge_index[0]
    const int* dsts = ei + N_EDGES;   // edge_index[1]

    char* ws = (char*)d_ws;
    size_t off = 0;
    auto alloc = [&](size_t bytes) { void* p = ws + off; off = (off + bytes + 255) & ~(size_t)255; return p; };
    float*  xt     = (float*)alloc((size_t)N_NODES * F * 4);
    float2* sd     = (float2*)alloc((size_t)N_NODES * 8);
    int*    deg    = (int*)alloc((size_t)N_NODES * 4);
    int*    part   = (int*)alloc((size_t)N_NODES * 4);
    int*    bsum   = (int*)alloc((size_t)NB * 4);
    int*    offs   = (int*)alloc((size_t)(N_NODES + 1) * 4);
    int*    cursor = (int*)alloc((size_t)N_NODES * 4);
    int2*   csr    = (int2*)alloc((size_t)ETOT * 8);

    hipMemsetAsync(deg, 0, (size_t)N_NODES * 4, stream);

    k_xt<<<(N_NODES + 3) / 4, 256, 0, stream>>>(x, W, a, xt, sd);
    k_hist<<<(N_EDGES + 255) / 256, 256, 0, stream>>>(srcs, dsts, deg);
    k_scanA<<<NB, SCAN_B, 0, stream>>>(deg, part, bsum);
    k_scanB<<<1, 64, 0, stream>>>(bsum);
    k_scanC<<<NB, SCAN_B, 0, stream>>>(part, bsum, offs, cursor);
    k_scatter<<<(N_EDGES + N_NODES + 255) / 256, 256, 0, stream>>>(srcs, dsts, sd, ea, a, cursor, csr);
    k_node<<<((size_t)N_NODES * 64 + 255) / 256, 256, 0, stream>>>(offs, csr, xt, out);
}

// Round 4
// 214.998 us; speedup vs baseline: 2.7122x; 1.2274x over previous
//
#include <hip/hip_runtime.h>
#include <hip/hip_fp16.h>

#define N_NODES 50000
#define N_EDGES 800000
#define ETOT    (2 * N_EDGES + N_NODES)   // 1,650,000
#define F       64
#define NEG_SLOPE 0.2f
#define SCAN_B  1024
#define NB      ((N_NODES + SCAN_B - 1) / SCAN_B)   // 49 (<= 64)

__device__ __forceinline__ float leaky(float v) {
    return (v > 0.f) ? v : NEG_SLOPE * v;
}
__device__ __forceinline__ unsigned int pack_entry(int src, float logit) {
    __half h = __float2half(logit);
    return (unsigned int)(unsigned short)src |
           ((unsigned int)__half_as_ushort(h) << 16);
}

// ---------------- xt = x @ W ; sd[n] = {xt.a[:64], xt.a[64:128]} ----------------
__global__ void k_xt(const float* __restrict__ x, const float* __restrict__ W,
                     const float* __restrict__ a, float* __restrict__ xt,
                     float2* __restrict__ sd) {
    __shared__ float Wl[64 * 64];
    __shared__ float xs[4][64];
    const int tid = threadIdx.x;
    for (int i = tid; i < 64 * 64; i += 256) Wl[i] = W[i];
    const int wid  = tid >> 6;
    const int lane = tid & 63;
    const int node = blockIdx.x * 4 + wid;
    if (node < N_NODES) xs[wid][lane] = x[node * F + lane];
    __syncthreads();
    if (node >= N_NODES) return;
    float acc = 0.f;
#pragma unroll
    for (int k = 0; k < 64; ++k) acc += xs[wid][k] * Wl[k * 64 + lane];
    xt[node * F + lane] = acc;
    float ps = acc * a[lane];
    float pd = acc * a[64 + lane];
#pragma unroll
    for (int off = 32; off >= 1; off >>= 1) {
        ps += __shfl_xor(ps, off);
        pd += __shfl_xor(pd, off);
    }
    if (lane == 0) sd[node] = make_float2(ps, pd);
}

// ---------------- e_contrib = edge_attr @ a[128:144] ----------------
__global__ void k_edge(const float* __restrict__ ea, const float* __restrict__ a,
                       float* __restrict__ ec) {
    const int e = blockIdx.x * blockDim.x + threadIdx.x;
    if (e >= N_EDGES) return;
    const float4* p = (const float4*)(ea + (size_t)e * 16);
    float acc = 0.f;
#pragma unroll
    for (int i = 0; i < 4; ++i) {
        float4 v = p[i];
        acc += v.x * a[128 + i * 4 + 0] + v.y * a[128 + i * 4 + 1] +
               v.z * a[128 + i * 4 + 2] + v.w * a[128 + i * 4 + 3];
    }
    ec[e] = acc;
}

// ---------------- histogram + per-edge rank capture ----------------
__global__ void k_hist(const int* __restrict__ srcs, const int* __restrict__ dsts,
                       int* __restrict__ deg, int2* __restrict__ rank) {
    const int t = blockIdx.x * blockDim.x + threadIdx.x;
    if (t >= N_EDGES) return;
    const int r1 = atomicAdd(&deg[dsts[t]], 1);   // dir s->d lands in dst list
    const int r2 = atomicAdd(&deg[srcs[t]], 1);   // dir d->s lands in src list
    rank[t] = make_int2(r1, r2);
}

// ---------------- exclusive scan, 2-level ----------------
__global__ void k_scanA(const int* __restrict__ deg, int* __restrict__ part,
                        int* __restrict__ bsum) {
    __shared__ int wtot[16];
    __shared__ int wexc[16];
    const int tid = threadIdx.x, lane = tid & 63, wid = tid >> 6;
    const int i = blockIdx.x * SCAN_B + tid;
    const int v = (i < N_NODES) ? (deg[i] + 1) : 0;   // +1 = self-loop
    int s = v;
#pragma unroll
    for (int off = 1; off < 64; off <<= 1) { int u = __shfl_up(s, off); if (lane >= off) s += u; }
    if (lane == 63) wtot[wid] = s;
    __syncthreads();
    if (tid == 0) { int run = 0; for (int w = 0; w < 16; ++w) { wexc[w] = run; run += wtot[w]; } bsum[blockIdx.x] = run; }
    __syncthreads();
    if (i < N_NODES) part[i] = wexc[wid] + s - v;
}

__global__ void k_scanB(int* __restrict__ bsum) {
    const int lane = threadIdx.x;
    const int v = (lane < NB) ? bsum[lane] : 0;
    int s = v;
#pragma unroll
    for (int off = 1; off < 64; off <<= 1) { int u = __shfl_up(s, off); if (lane >= off) s += u; }
    if (lane < NB) bsum[lane] = s - v;
}

__global__ void k_scanC(const int* __restrict__ part, const int* __restrict__ bsum,
                        int* __restrict__ offs) {
    const int i = blockIdx.x * SCAN_B + threadIdx.x;
    if (i < N_NODES) offs[i] = part[i] + bsum[blockIdx.x];
    if (i == 0) offs[N_NODES] = ETOT;
}

// ---------------- scatter: no atomics, pos = offs[dst] + precomputed rank ----------
__global__ void k_scatter(const int* __restrict__ srcs, const int* __restrict__ dsts,
                          const float2* __restrict__ sd, const float* __restrict__ ec,
                          const int2* __restrict__ rank, const int* __restrict__ offs,
                          const int* __restrict__ deg, unsigned int* __restrict__ csr) {
    const int t = blockIdx.x * blockDim.x + threadIdx.x;
    if (t < N_EDGES) {
        const int s = srcs[t], d = dsts[t];
        const float e = ec[t];
        const int2 r = rank[t];
        const float2 ss = sd[s], dd = sd[d];
        const float v1 = leaky(ss.x + dd.y + e);   // src=s -> dst=d
        const float v2 = leaky(dd.x + ss.y + e);   // src=d -> dst=s
        csr[offs[d] + r.x] = pack_entry(s, v1);
        csr[offs[s] + r.y] = pack_entry(d, v2);
    } else if (t < N_EDGES + N_NODES) {
        const int n = t - N_EDGES;
        const float2 nn = sd[n];
        csr[offs[n] + deg[n]] = pack_entry(n, leaky(nn.x + nn.y));
    }
}

// ---------------- wave-per-node: softmax + weighted feature gather ----------------
__global__ void k_node(const int* __restrict__ offs, const unsigned int* __restrict__ csr,
                       const float* __restrict__ xt, float* __restrict__ out) {
    const int node = (blockIdx.x * blockDim.x + threadIdx.x) >> 6;
    const int lane = threadIdx.x & 63;
    if (node >= N_NODES) return;
    const int beg = offs[node], end = offs[node + 1];
    // phase 1: max
    float m = -1e30f;
    for (int j = beg + lane; j < end; j += 64)
        m = fmaxf(m, __half2float(__ushort_as_half((unsigned short)(csr[j] >> 16))));
#pragma unroll
    for (int off = 32; off >= 1; off >>= 1) m = fmaxf(m, __shfl_xor(m, off));
    // phase 2: sum exp
    float sum = 0.f;
    for (int j = beg + lane; j < end; j += 64)
        sum += __expf(__half2float(__ushort_as_half((unsigned short)(csr[j] >> 16))) - m);
#pragma unroll
    for (int off = 32; off >= 1; off >>= 1) sum += __shfl_xor(sum, off);
    const float inv = 1.0f / sum;
    // phase 3: 4-way j-parallel, 16 feature-chunks of float4
    const int jg = lane >> 4;        // 0..3
    const int fc = lane & 15;        // 0..15
    float4 acc = make_float4(0.f, 0.f, 0.f, 0.f);
    for (int j = beg + jg; j < end; j += 4) {
        const unsigned int ent = csr[j];
        const int   src = (int)(ent & 0xFFFFu);
        const float lg  = __half2float(__ushort_as_half((unsigned short)(ent >> 16)));
        const float att = __expf(lg - m) * inv;
        const float4 v = *(const float4*)(xt + (size_t)src * F + fc * 4);
        acc.x += att * v.x; acc.y += att * v.y; acc.z += att * v.z; acc.w += att * v.w;
    }
#pragma unroll
    for (int off = 16; off <= 32; off <<= 1) {
        acc.x += __shfl_xor(acc.x, off);
        acc.y += __shfl_xor(acc.y, off);
        acc.z += __shfl_xor(acc.z, off);
        acc.w += __shfl_xor(acc.w, off);
    }
    if (jg == 0) *(float4*)(out + (size_t)node * F + fc * 4) = acc;
}

extern "C" void kernel_launch(void* const* d_in, const int* in_sizes, int n_in,
                              void* d_out, int out_size, void* d_ws, size_t ws_size,
                              hipStream_t stream) {
    const float* x    = (const float*)d_in[0];
    const int*   ei   = (const int*)d_in[1];
    const float* ea   = (const float*)d_in[2];
    const float* W    = (const float*)d_in[4];
    const float* a    = (const float*)d_in[5];
    float* out = (float*)d_out;

    const int* srcs = ei;             // edge_index[0]
    const int* dsts = ei + N_EDGES;   // edge_index[1]

    char* ws = (char*)d_ws;
    size_t off = 0;
    auto alloc = [&](size_t bytes) { void* p = ws + off; off = (off + bytes + 255) & ~(size_t)255; return p; };
    float*        xt   = (float*)alloc((size_t)N_NODES * F * 4);
    float2*       sd   = (float2*)alloc((size_t)N_NODES * 8);
    float*        ec   = (float*)alloc((size_t)N_EDGES * 4);
    int*          deg  = (int*)alloc((size_t)N_NODES * 4);
    int*          part = (int*)alloc((size_t)N_NODES * 4);
    int*          bsum = (int*)alloc((size_t)NB * 4);
    int*          offs = (int*)alloc((size_t)(N_NODES + 1) * 4);
    int2*         rank = (int2*)alloc((size_t)N_EDGES * 8);
    unsigned int* csr  = (unsigned int*)alloc((size_t)ETOT * 4);

    hipMemsetAsync(deg, 0, (size_t)N_NODES * 4, stream);

    k_xt<<<(N_NODES + 3) / 4, 256, 0, stream>>>(x, W, a, xt, sd);
    k_edge<<<(N_EDGES + 255) / 256, 256, 0, stream>>>(ea, a, ec);
    k_hist<<<(N_EDGES + 255) / 256, 256, 0, stream>>>(srcs, dsts, deg, rank);
    k_scanA<<<NB, SCAN_B, 0, stream>>>(deg, part, bsum);
    k_scanB<<<1, 64, 0, stream>>>(bsum);
    k_scanC<<<NB, SCAN_B, 0, stream>>>(part, bsum, offs);
    k_scatter<<<(N_EDGES + N_NODES + 255) / 256, 256, 0, stream>>>(srcs, dsts, sd, ec, rank, offs, deg, csr);
    k_node<<<((size_t)N_NODES * 64 + 255) / 256, 256, 0, stream>>>(offs, csr, xt, out);
}

// Round 5
// 201.340 us; speedup vs baseline: 2.8961x; 1.0678x over previous
//
#include <hip/hip_runtime.h>
#include <hip/hip_fp16.h>

#define N_NODES 50000
#define N_EDGES 800000
#define ETOT    (2 * N_EDGES + N_NODES)   // 1,650,000
#define F       64
#define NEG_SLOPE 0.2f
#define SCAN_B  1024
#define NB      ((N_NODES + SCAN_B - 1) / SCAN_B)   // 49 (<= 64)

#define RSPLIT  4
#define NRANGE  (N_NODES / RSPLIT)        // 12500 nodes -> 50 KB LDS
#define CCHUNK  64
#define EPC     (N_EDGES / CCHUNK)        // 12500 edges per chunk

__device__ __forceinline__ float leaky(float v) {
    return (v > 0.f) ? v : NEG_SLOPE * v;
}
__device__ __forceinline__ unsigned int pack_entry(int src, float logit) {
    __half h = __float2half(logit);
    return (unsigned int)(unsigned short)src |
           ((unsigned int)__half_as_ushort(h) << 16);
}

// ---------------- xt = x @ W ; sd[n] = {xt.a[:64], xt.a[64:128]} ----------------
__global__ void k_xt(const float* __restrict__ x, const float* __restrict__ W,
                     const float* __restrict__ a, float* __restrict__ xt,
                     float2* __restrict__ sd) {
    __shared__ float Wl[64 * 64];
    __shared__ float xs[4][64];
    const int tid = threadIdx.x;
    for (int i = tid; i < 64 * 64; i += 256) Wl[i] = W[i];
    const int wid  = tid >> 6;
    const int lane = tid & 63;
    const int node = blockIdx.x * 4 + wid;
    if (node < N_NODES) xs[wid][lane] = x[node * F + lane];
    __syncthreads();
    if (node >= N_NODES) return;
    float acc = 0.f;
#pragma unroll
    for (int k = 0; k < 64; ++k) acc += xs[wid][k] * Wl[k * 64 + lane];
    xt[node * F + lane] = acc;
    float ps = acc * a[lane];
    float pd = acc * a[64 + lane];
#pragma unroll
    for (int off = 32; off >= 1; off >>= 1) {
        ps += __shfl_xor(ps, off);
        pd += __shfl_xor(pd, off);
    }
    if (lane == 0) sd[node] = make_float2(ps, pd);
}

// ---------------- e_contrib = edge_attr @ a[128:144] ----------------
__global__ void k_edge(const float* __restrict__ ea, const float* __restrict__ a,
                       float* __restrict__ ec) {
    const int e = blockIdx.x * blockDim.x + threadIdx.x;
    if (e >= N_EDGES) return;
    const float4* p = (const float4*)(ea + (size_t)e * 16);
    float acc = 0.f;
#pragma unroll
    for (int i = 0; i < 4; ++i) {
        float4 v = p[i];
        acc += v.x * a[128 + i * 4 + 0] + v.y * a[128 + i * 4 + 1] +
               v.z * a[128 + i * 4 + 2] + v.w * a[128 + i * 4 + 3];
    }
    ec[e] = acc;
}

// ---------------- per-(chunk,range) LDS histogram -> cnt[c][n] (no global atomics) ----
__global__ void __launch_bounds__(256) k_histA(const int* __restrict__ srcs,
                                               const int* __restrict__ dsts,
                                               int* __restrict__ cnt) {
    __shared__ int h[NRANGE];
    const int c = blockIdx.x / RSPLIT, r = blockIdx.x % RSPLIT;
    const int nbase = r * NRANGE;
    for (int i = threadIdx.x; i < NRANGE; i += 256) h[i] = 0;
    __syncthreads();
    const int e0 = c * EPC;
    for (int i = e0 + threadIdx.x; i < e0 + EPC; i += 256) {
        const int d = dsts[i] - nbase;
        if ((unsigned)d < NRANGE) atomicAdd(&h[d], 1);
        const int s = srcs[i] - nbase;
        if ((unsigned)s < NRANGE) atomicAdd(&h[s], 1);
    }
    __syncthreads();
    int* o = cnt + (size_t)c * N_NODES + nbase;
    for (int i = threadIdx.x; i < NRANGE; i += 256) o[i] = h[i];
}

// ---------------- per-node prefix over chunks (in-place) + 2-level node scan ----------
__global__ void k_scanA(int* __restrict__ cnt, int* __restrict__ part,
                        int* __restrict__ bsum) {
    __shared__ int wtot[16];
    __shared__ int wexc[16];
    const int tid = threadIdx.x, lane = tid & 63, wid = tid >> 6;
    const int i = blockIdx.x * SCAN_B + tid;
    int v = 0;
    if (i < N_NODES) {
        int run = 0;
#pragma unroll 8
        for (int c = 0; c < CCHUNK; ++c) {
            const int t = cnt[(size_t)c * N_NODES + i];
            cnt[(size_t)c * N_NODES + i] = run;   // exclusive prefix for chunk c
            run += t;
        }
        v = run + 1;   // +1 = self-loop
    }
    int s = v;
#pragma unroll
    for (int off = 1; off < 64; off <<= 1) { int u = __shfl_up(s, off); if (lane >= off) s += u; }
    if (lane == 63) wtot[wid] = s;
    __syncthreads();
    if (tid == 0) { int run = 0; for (int w = 0; w < 16; ++w) { wexc[w] = run; run += wtot[w]; } bsum[blockIdx.x] = run; }
    __syncthreads();
    if (i < N_NODES) part[i] = wexc[wid] + s - v;
}

__global__ void k_scanB(int* __restrict__ bsum) {
    const int lane = threadIdx.x;
    const int v = (lane < NB) ? bsum[lane] : 0;
    int s = v;
#pragma unroll
    for (int off = 1; off < 64; off <<= 1) { int u = __shfl_up(s, off); if (lane >= off) s += u; }
    if (lane < NB) bsum[lane] = s - v;
}

__global__ void k_scanC(const int* __restrict__ part, const int* __restrict__ bsum,
                        int* __restrict__ offs) {
    const int i = blockIdx.x * SCAN_B + threadIdx.x;
    if (i < N_NODES) offs[i] = part[i] + bsum[blockIdx.x];
    if (i == 0) offs[N_NODES] = ETOT;
}

// ---------------- scatter with LDS cursors: pos unique, no global atomics ----------
__global__ void __launch_bounds__(256) k_scatter(const int* __restrict__ srcs,
                                                 const int* __restrict__ dsts,
                                                 const float2* __restrict__ sd,
                                                 const float* __restrict__ ec,
                                                 const int* __restrict__ cnt,
                                                 const int* __restrict__ offs,
                                                 unsigned int* __restrict__ csr) {
    __shared__ int cur[NRANGE];
    const int c = blockIdx.x / RSPLIT, r = blockIdx.x % RSPLIT;
    const int nbase = r * NRANGE;
    const int* cslice = cnt + (size_t)c * N_NODES + nbase;
    const int* oslice = offs + nbase;
    for (int i = threadIdx.x; i < NRANGE; i += 256) cur[i] = oslice[i] + cslice[i];
    __syncthreads();
    const int e0 = c * EPC;
    for (int i = e0 + threadIdx.x; i < e0 + EPC; i += 256) {
        const int s = srcs[i], d = dsts[i];
        const int dl = d - nbase, sl = s - nbase;
        const bool din = (unsigned)dl < NRANGE;
        const bool sin_ = (unsigned)sl < NRANGE;
        if (!din && !sin_) continue;
        const float e = ec[i];
        const float2 ss = sd[s], dd = sd[d];
        if (din) {   // direction s -> d
            const int pos = atomicAdd(&cur[dl], 1);
            csr[pos] = pack_entry(s, leaky(ss.x + dd.y + e));
        }
        if (sin_) {  // direction d -> s
            const int pos = atomicAdd(&cur[sl], 1);
            csr[pos] = pack_entry(d, leaky(dd.x + ss.y + e));
        }
    }
}

// ---------------- self-loop entries: last slot of each node's segment ----------
__global__ void k_self(const float2* __restrict__ sd, const int* __restrict__ offs,
                       unsigned int* __restrict__ csr) {
    const int n = blockIdx.x * blockDim.x + threadIdx.x;
    if (n >= N_NODES) return;
    const float2 v = sd[n];
    csr[offs[n + 1] - 1] = pack_entry(n, leaky(v.x + v.y));
}

// ---------------- wave-per-node: softmax + weighted feature gather ----------------
__global__ void k_node(const int* __restrict__ offs, const unsigned int* __restrict__ csr,
                       const float* __restrict__ xt, float* __restrict__ out) {
    const int node = (blockIdx.x * blockDim.x + threadIdx.x) >> 6;
    const int lane = threadIdx.x & 63;
    if (node >= N_NODES) return;
    const int beg = offs[node], end = offs[node + 1];
    // phase 1: max
    float m = -1e30f;
    for (int j = beg + lane; j < end; j += 64)
        m = fmaxf(m, __half2float(__ushort_as_half((unsigned short)(csr[j] >> 16))));
#pragma unroll
    for (int off = 32; off >= 1; off >>= 1) m = fmaxf(m, __shfl_xor(m, off));
    // phase 2: sum exp
    float sum = 0.f;
    for (int j = beg + lane; j < end; j += 64)
        sum += __expf(__half2float(__ushort_as_half((unsigned short)(csr[j] >> 16))) - m);
#pragma unroll
    for (int off = 32; off >= 1; off >>= 1) sum += __shfl_xor(sum, off);
    const float inv = 1.0f / sum;
    // phase 3: 4-way j-parallel, 16 feature-chunks of float4
    const int jg = lane >> 4;        // 0..3
    const int fc = lane & 15;        // 0..15
    float4 acc = make_float4(0.f, 0.f, 0.f, 0.f);
    for (int j = beg + jg; j < end; j += 4) {
        const unsigned int ent = csr[j];
        const int   src = (int)(ent & 0xFFFFu);
        const float lg  = __half2float(__ushort_as_half((unsigned short)(ent >> 16)));
        const float att = __expf(lg - m) * inv;
        const float4 v = *(const float4*)(xt + (size_t)src * F + fc * 4);
        acc.x += att * v.x; acc.y += att * v.y; acc.z += att * v.z; acc.w += att * v.w;
    }
#pragma unroll
    for (int off = 16; off <= 32; off <<= 1) {
        acc.x += __shfl_xor(acc.x, off);
        acc.y += __shfl_xor(acc.y, off);
        acc.z += __shfl_xor(acc.z, off);
        acc.w += __shfl_xor(acc.w, off);
    }
    if (jg == 0) *(float4*)(out + (size_t)node * F + fc * 4) = acc;
}

extern "C" void kernel_launch(void* const* d_in, const int* in_sizes, int n_in,
                              void* d_out, int out_size, void* d_ws, size_t ws_size,
                              hipStream_t stream) {
    const float* x    = (const float*)d_in[0];
    const int*   ei   = (const int*)d_in[1];
    const float* ea   = (const float*)d_in[2];
    const float* W    = (const float*)d_in[4];
    const float* a    = (const float*)d_in[5];
    float* out = (float*)d_out;

    const int* srcs = ei;             // edge_index[0]
    const int* dsts = ei + N_EDGES;   // edge_index[1]

    char* ws = (char*)d_ws;
    size_t off = 0;
    auto alloc = [&](size_t bytes) { void* p = ws + off; off = (off + bytes + 255) & ~(size_t)255; return p; };
    float*        xt   = (float*)alloc((size_t)N_NODES * F * 4);
    float2*       sd   = (float2*)alloc((size_t)N_NODES * 8);
    float*        ec   = (float*)alloc((size_t)N_EDGES * 4);
    int*          cnt  = (int*)alloc((size_t)CCHUNK * N_NODES * 4);   // 12.8 MB
    int*          part = (int*)alloc((size_t)N_NODES * 4);
    int*          bsum = (int*)alloc((size_t)NB * 4);
    int*          offs = (int*)alloc((size_t)(N_NODES + 1) * 4);
    unsigned int* csr  = (unsigned int*)alloc((size_t)ETOT * 4);

    k_xt<<<(N_NODES + 3) / 4, 256, 0, stream>>>(x, W, a, xt, sd);
    k_edge<<<(N_EDGES + 255) / 256, 256, 0, stream>>>(ea, a, ec);
    k_histA<<<CCHUNK * RSPLIT, 256, 0, stream>>>(srcs, dsts, cnt);
    k_scanA<<<NB, SCAN_B, 0, stream>>>(cnt, part, bsum);
    k_scanB<<<1, 64, 0, stream>>>(bsum);
    k_scanC<<<NB, SCAN_B, 0, stream>>>(part, bsum, offs);
    k_scatter<<<CCHUNK * RSPLIT, 256, 0, stream>>>(srcs, dsts, sd, ec, cnt, offs, csr);
    k_self<<<(N_NODES + 255) / 256, 256, 0, stream>>>(sd, offs, csr);
    k_node<<<((size_t)N_NODES * 64 + 255) / 256, 256, 0, stream>>>(offs, csr, xt, out);
}

// Round 6
// 177.215 us; speedup vs baseline: 3.2904x; 1.1361x over previous
//
#include <hip/hip_runtime.h>
#include <hip/hip_fp16.h>

#define N_NODES 50000
#define N_EDGES 800000
#define ETOT    (2 * N_EDGES + N_NODES)   // 1,650,000
#define F       64
#define NEG_SLOPE 0.2f
#define SCAN_B  1024
#define NB      ((N_NODES + SCAN_B - 1) / SCAN_B)   // 49 (<= 64)

#define RSPLIT  4
#define NRANGE  (N_NODES / RSPLIT)        // 12500 nodes -> 50 KB LDS
#define CCHUNK  64
#define EPC     (N_EDGES / CCHUNK)        // 12500 edges per chunk

__device__ __forceinline__ float leaky(float v) {
    return (v > 0.f) ? v : NEG_SLOPE * v;
}
// entry = src (low16) | fp16(exp(leaky(logit))) (high16)
__device__ __forceinline__ unsigned int pack_entry(int src, float w) {
    __half h = __float2half(w);
    return (unsigned int)(unsigned short)src |
           ((unsigned int)__half_as_ushort(h) << 16);
}

// ---------------- xt = x @ W (fp16 out) ; sd[n] = {xt.a[:64], xt.a[64:128]} -------
__global__ void k_xt(const float* __restrict__ x, const float* __restrict__ W,
                     const float* __restrict__ a, __half* __restrict__ xt,
                     float2* __restrict__ sd) {
    __shared__ float Wl[64 * 64];
    __shared__ float xs[4][64];
    const int tid = threadIdx.x;
    for (int i = tid; i < 64 * 64; i += 256) Wl[i] = W[i];
    const int wid  = tid >> 6;
    const int lane = tid & 63;
    const int node = blockIdx.x * 4 + wid;
    if (node < N_NODES) xs[wid][lane] = x[node * F + lane];
    __syncthreads();
    if (node >= N_NODES) return;
    float acc = 0.f;
#pragma unroll
    for (int k = 0; k < 64; ++k) acc += xs[wid][k] * Wl[k * 64 + lane];
    xt[node * F + lane] = __float2half(acc);
    float ps = acc * a[lane];
    float pd = acc * a[64 + lane];
#pragma unroll
    for (int off = 32; off >= 1; off >>= 1) {
        ps += __shfl_xor(ps, off);
        pd += __shfl_xor(pd, off);
    }
    if (lane == 0) sd[node] = make_float2(ps, pd);
}

// ---------------- e_contrib = edge_attr @ a[128:144] ----------------
__global__ void k_edge(const float* __restrict__ ea, const float* __restrict__ a,
                       float* __restrict__ ec) {
    const int e = blockIdx.x * blockDim.x + threadIdx.x;
    if (e >= N_EDGES) return;
    const float4* p = (const float4*)(ea + (size_t)e * 16);
    float acc = 0.f;
#pragma unroll
    for (int i = 0; i < 4; ++i) {
        float4 v = p[i];
        acc += v.x * a[128 + i * 4 + 0] + v.y * a[128 + i * 4 + 1] +
               v.z * a[128 + i * 4 + 2] + v.w * a[128 + i * 4 + 3];
    }
    ec[e] = acc;
}

// ---------------- per-(chunk,range) LDS histogram -> cnt[c][n] (no global atomics) ----
__global__ void __launch_bounds__(256) k_histA(const int* __restrict__ srcs,
                                               const int* __restrict__ dsts,
                                               int* __restrict__ cnt) {
    __shared__ int h[NRANGE];
    const int c = blockIdx.x / RSPLIT, r = blockIdx.x % RSPLIT;
    const int nbase = r * NRANGE;
    for (int i = threadIdx.x; i < NRANGE; i += 256) h[i] = 0;
    __syncthreads();
    const int e0 = c * EPC;
    for (int i = e0 + threadIdx.x; i < e0 + EPC; i += 256) {
        const int d = dsts[i] - nbase;
        if ((unsigned)d < NRANGE) atomicAdd(&h[d], 1);
        const int s = srcs[i] - nbase;
        if ((unsigned)s < NRANGE) atomicAdd(&h[s], 1);
    }
    __syncthreads();
    int* o = cnt + (size_t)c * N_NODES + nbase;
    for (int i = threadIdx.x; i < NRANGE; i += 256) o[i] = h[i];
}

// ---------------- per-node prefix over chunks (in-place) + 2-level node scan ----------
__global__ void k_scanA(int* __restrict__ cnt, int* __restrict__ part,
                        int* __restrict__ bsum) {
    __shared__ int wtot[16];
    __shared__ int wexc[16];
    const int tid = threadIdx.x, lane = tid & 63, wid = tid >> 6;
    const int i = blockIdx.x * SCAN_B + tid;
    int v = 0;
    if (i < N_NODES) {
        int run = 0;
#pragma unroll 8
        for (int c = 0; c < CCHUNK; ++c) {
            const int t = cnt[(size_t)c * N_NODES + i];
            cnt[(size_t)c * N_NODES + i] = run;   // exclusive prefix for chunk c
            run += t;
        }
        v = run + 1;   // +1 = self-loop
    }
    int s = v;
#pragma unroll
    for (int off = 1; off < 64; off <<= 1) { int u = __shfl_up(s, off); if (lane >= off) s += u; }
    if (lane == 63) wtot[wid] = s;
    __syncthreads();
    if (tid == 0) { int run = 0; for (int w = 0; w < 16; ++w) { wexc[w] = run; run += wtot[w]; } bsum[blockIdx.x] = run; }
    __syncthreads();
    if (i < N_NODES) part[i] = wexc[wid] + s - v;
}

__global__ void k_scanB(int* __restrict__ bsum) {
    const int lane = threadIdx.x;
    const int v = (lane < NB) ? bsum[lane] : 0;
    int s = v;
#pragma unroll
    for (int off = 1; off < 64; off <<= 1) { int u = __shfl_up(s, off); if (lane >= off) s += u; }
    if (lane < NB) bsum[lane] = s - v;
}

__global__ void k_scanC(const int* __restrict__ part, const int* __restrict__ bsum,
                        int* __restrict__ offs) {
    const int i = blockIdx.x * SCAN_B + threadIdx.x;
    if (i < N_NODES) offs[i] = part[i] + bsum[blockIdx.x];
    if (i == 0) offs[N_NODES] = ETOT;
}

// ---------------- scatter with LDS cursors: stores exp-weights, no global atomics ----
__global__ void __launch_bounds__(256) k_scatter(const int* __restrict__ srcs,
                                                 const int* __restrict__ dsts,
                                                 const float2* __restrict__ sd,
                                                 const float* __restrict__ ec,
                                                 const int* __restrict__ cnt,
                                                 const int* __restrict__ offs,
                                                 unsigned int* __restrict__ csr) {
    __shared__ int cur[NRANGE];
    const int c = blockIdx.x / RSPLIT, r = blockIdx.x % RSPLIT;
    const int nbase = r * NRANGE;
    const int* cslice = cnt + (size_t)c * N_NODES + nbase;
    const int* oslice = offs + nbase;
    for (int i = threadIdx.x; i < NRANGE; i += 256) cur[i] = oslice[i] + cslice[i];
    __syncthreads();
    const int e0 = c * EPC;
    for (int i = e0 + threadIdx.x; i < e0 + EPC; i += 256) {
        const int s = srcs[i], d = dsts[i];
        const int dl = d - nbase, sl = s - nbase;
        const bool din = (unsigned)dl < NRANGE;
        const bool sin_ = (unsigned)sl < NRANGE;
        if (!din && !sin_) continue;
        const float e = ec[i];
        const float2 ss = sd[s], dd = sd[d];
        if (din) {   // direction s -> d
            const int pos = atomicAdd(&cur[dl], 1);
            csr[pos] = pack_entry(s, __expf(leaky(ss.x + dd.y + e)));
        }
        if (sin_) {  // direction d -> s
            const int pos = atomicAdd(&cur[sl], 1);
            csr[pos] = pack_entry(d, __expf(leaky(dd.x + ss.y + e)));
        }
    }
}

// ---------------- self-loop entries: last slot of each node's segment ----------
__global__ void k_self(const float2* __restrict__ sd, const int* __restrict__ offs,
                       unsigned int* __restrict__ csr) {
    const int n = blockIdx.x * blockDim.x + threadIdx.x;
    if (n >= N_NODES) return;
    const float2 v = sd[n];
    csr[offs[n + 1] - 1] = pack_entry(n, __expf(leaky(v.x + v.y)));
}

// ---------------- wave-per-node, single pass: acc += w*xt[src]; out = acc/Σw --------
__global__ void k_node(const int* __restrict__ offs, const unsigned int* __restrict__ csr,
                       const __half* __restrict__ xt, float* __restrict__ out) {
    const int node = (blockIdx.x * blockDim.x + threadIdx.x) >> 6;
    const int lane = threadIdx.x & 63;
    if (node >= N_NODES) return;
    const int beg = offs[node], end = offs[node + 1];
    const int jg = lane >> 3;        // 0..7  (8-way edge parallelism)
    const int fc = lane & 7;         // 0..7  (8 halves per lane)
    float acc[8] = {0.f, 0.f, 0.f, 0.f, 0.f, 0.f, 0.f, 0.f};
    float sum = 0.f;
    for (int j = beg + jg; j < end; j += 8) {
        const unsigned int ent = csr[j];
        const int   src = (int)(ent & 0xFFFFu);
        const float w   = __half2float(__ushort_as_half((unsigned short)(ent >> 16)));
        sum += w;
        const uint4 hv = *(const uint4*)(xt + (size_t)src * F + fc * 8);
        const __half2* hp = (const __half2*)&hv;
#pragma unroll
        for (int k = 0; k < 4; ++k) {
            const float2 f = __half22float2(hp[k]);
            acc[2 * k]     += w * f.x;
            acc[2 * k + 1] += w * f.y;
        }
    }
    // reduce across jg (lane bits 3..5)
#pragma unroll
    for (int off = 8; off <= 32; off <<= 1) {
        sum += __shfl_xor(sum, off);
#pragma unroll
        for (int k = 0; k < 8; ++k) acc[k] += __shfl_xor(acc[k], off);
    }
    if (jg == 0) {
        const float inv = 1.0f / sum;
        float4* op = (float4*)(out + (size_t)node * F + fc * 8);
        op[0] = make_float4(acc[0] * inv, acc[1] * inv, acc[2] * inv, acc[3] * inv);
        op[1] = make_float4(acc[4] * inv, acc[5] * inv, acc[6] * inv, acc[7] * inv);
    }
}

extern "C" void kernel_launch(void* const* d_in, const int* in_sizes, int n_in,
                              void* d_out, int out_size, void* d_ws, size_t ws_size,
                              hipStream_t stream) {
    const float* x    = (const float*)d_in[0];
    const int*   ei   = (const int*)d_in[1];
    const float* ea   = (const float*)d_in[2];
    const float* W    = (const float*)d_in[4];
    const float* a    = (const float*)d_in[5];
    float* out = (float*)d_out;

    const int* srcs = ei;             // edge_index[0]
    const int* dsts = ei + N_EDGES;   // edge_index[1]

    char* ws = (char*)d_ws;
    size_t off = 0;
    auto alloc = [&](size_t bytes) { void* p = ws + off; off = (off + bytes + 255) & ~(size_t)255; return p; };
    __half*       xt   = (__half*)alloc((size_t)N_NODES * F * 2);
    float2*       sd   = (float2*)alloc((size_t)N_NODES * 8);
    float*        ec   = (float*)alloc((size_t)N_EDGES * 4);
    int*          cnt  = (int*)alloc((size_t)CCHUNK * N_NODES * 4);   // 12.8 MB
    int*          part = (int*)alloc((size_t)N_NODES * 4);
    int*          bsum = (int*)alloc((size_t)NB * 4);
    int*          offs = (int*)alloc((size_t)(N_NODES + 1) * 4);
    unsigned int* csr  = (unsigned int*)alloc((size_t)ETOT * 4);

    k_xt<<<(N_NODES + 3) / 4, 256, 0, stream>>>(x, W, a, xt, sd);
    k_edge<<<(N_EDGES + 255) / 256, 256, 0, stream>>>(ea, a, ec);
    k_histA<<<CCHUNK * RSPLIT, 256, 0, stream>>>(srcs, dsts, cnt);
    k_scanA<<<NB, SCAN_B, 0, stream>>>(cnt, part, bsum);
    k_scanB<<<1, 64, 0, stream>>>(bsum);
    k_scanC<<<NB, SCAN_B, 0, stream>>>(part, bsum, offs);
    k_scatter<<<CCHUNK * RSPLIT, 256, 0, stream>>>(srcs, dsts, sd, ec, cnt, offs, csr);
    k_self<<<(N_NODES + 255) / 256, 256, 0, stream>>>(sd, offs, csr);
    k_node<<<((size_t)N_NODES * 64 + 255) / 256, 256, 0, stream>>>(offs, csr, xt, out);
}

// Round 7
// 137.432 us; speedup vs baseline: 4.2429x; 1.2895x over previous
//
#include <hip/hip_runtime.h>
#include <hip/hip_fp16.h>

#define N_NODES 50000
#define N_EDGES 800000
#define ETOT    (2 * N_EDGES + N_NODES)   // 1,650,000
#define F       64
#define NEG_SLOPE 0.2f
#define SCAN_B  1024
#define NB      ((N_NODES + SCAN_B - 1) / SCAN_B)   // 49 (<= 64)

#define RSPLIT  4
#define NRANGE  (N_NODES / RSPLIT)        // 12500 nodes -> 50 KB LDS
#define CCHUNK  64
#define EPC     (N_EDGES / CCHUNK)        // 12500 edges per chunk
#define BLD     1024                      // big blocks: 16 waves/CU for latency hiding

__device__ __forceinline__ float leaky(float v) {
    return (v > 0.f) ? v : NEG_SLOPE * v;
}
// entry = src (low16) | fp16(exp(leaky(logit))) (high16)
__device__ __forceinline__ unsigned int pack_entry(int src, float w) {
    __half h = __float2half(w);
    return (unsigned int)(unsigned short)src |
           ((unsigned int)__half_as_ushort(h) << 16);
}

// ---------------- xt = x @ W (fp16 out) ; sd[n] = {xt.a[:64], xt.a[64:128]} -------
__global__ void k_xt(const float* __restrict__ x, const float* __restrict__ W,
                     const float* __restrict__ a, __half* __restrict__ xt,
                     float2* __restrict__ sd) {
    __shared__ float Wl[64 * 64];
    __shared__ float xs[4][64];
    const int tid = threadIdx.x;
    for (int i = tid; i < 64 * 64; i += 256) Wl[i] = W[i];
    const int wid  = tid >> 6;
    const int lane = tid & 63;
    const int node = blockIdx.x * 4 + wid;
    if (node < N_NODES) xs[wid][lane] = x[node * F + lane];
    __syncthreads();
    if (node >= N_NODES) return;
    float acc = 0.f;
#pragma unroll
    for (int k = 0; k < 64; ++k) acc += xs[wid][k] * Wl[k * 64 + lane];
    xt[node * F + lane] = __float2half(acc);
    float ps = acc * a[lane];
    float pd = acc * a[64 + lane];
#pragma unroll
    for (int off = 32; off >= 1; off >>= 1) {
        ps += __shfl_xor(ps, off);
        pd += __shfl_xor(pd, off);
    }
    if (lane == 0) sd[node] = make_float2(ps, pd);
}

// ------- per-(chunk,range) LDS histogram -> cnt[c][n]; fused ec for 1/4 of chunk ----
__global__ void __launch_bounds__(BLD) k_histA(const int* __restrict__ srcs,
                                               const int* __restrict__ dsts,
                                               const float* __restrict__ ea,
                                               const float* __restrict__ a,
                                               float* __restrict__ ec,
                                               int* __restrict__ cnt) {
    __shared__ int h[NRANGE];
    const int c = blockIdx.x / RSPLIT, r = blockIdx.x % RSPLIT;
    const int nbase = r * NRANGE;
    for (int i = threadIdx.x; i < NRANGE; i += BLD) h[i] = 0;
    __syncthreads();
    const int e0 = c * EPC;
    for (int i = e0 + threadIdx.x; i < e0 + EPC; i += BLD) {
        const int d = dsts[i] - nbase;
        if ((unsigned)d < NRANGE) atomicAdd(&h[d], 1);
        const int s = srcs[i] - nbase;
        if ((unsigned)s < NRANGE) atomicAdd(&h[s], 1);
    }
    // fused ec: this block handles quarter r of chunk c
    const int eq0 = e0 + (r * EPC) / RSPLIT;
    const int eq1 = e0 + ((r + 1) * EPC) / RSPLIT;
    for (int i = eq0 + threadIdx.x; i < eq1; i += BLD) {
        const float4* p = (const float4*)(ea + (size_t)i * 16);
        float acc = 0.f;
#pragma unroll
        for (int k = 0; k < 4; ++k) {
            float4 v = p[k];
            acc += v.x * a[128 + k * 4 + 0] + v.y * a[128 + k * 4 + 1] +
                   v.z * a[128 + k * 4 + 2] + v.w * a[128 + k * 4 + 3];
        }
        ec[i] = acc;
    }
    __syncthreads();
    int* o = cnt + (size_t)c * N_NODES + nbase;
    for (int i = threadIdx.x; i < NRANGE; i += BLD) o[i] = h[i];
}

// ---------------- per-node prefix over chunks (in-place) + 2-level node scan ----------
__global__ void k_scanA(int* __restrict__ cnt, int* __restrict__ part,
                        int* __restrict__ bsum) {
    __shared__ int wtot[16];
    __shared__ int wexc[16];
    const int tid = threadIdx.x, lane = tid & 63, wid = tid >> 6;
    const int i = blockIdx.x * SCAN_B + tid;
    int v = 0;
    if (i < N_NODES) {
        int run = 0;
#pragma unroll 8
        for (int c = 0; c < CCHUNK; ++c) {
            const int t = cnt[(size_t)c * N_NODES + i];
            cnt[(size_t)c * N_NODES + i] = run;   // exclusive prefix for chunk c
            run += t;
        }
        v = run + 1;   // +1 = self-loop
    }
    int s = v;
#pragma unroll
    for (int off = 1; off < 64; off <<= 1) { int u = __shfl_up(s, off); if (lane >= off) s += u; }
    if (lane == 63) wtot[wid] = s;
    __syncthreads();
    if (tid == 0) { int run = 0; for (int w = 0; w < 16; ++w) { wexc[w] = run; run += wtot[w]; } bsum[blockIdx.x] = run; }
    __syncthreads();
    if (i < N_NODES) part[i] = wexc[wid] + s - v;
}

__global__ void k_scanB(int* __restrict__ bsum) {
    const int lane = threadIdx.x;
    const int v = (lane < NB) ? bsum[lane] : 0;
    int s = v;
#pragma unroll
    for (int off = 1; off < 64; off <<= 1) { int u = __shfl_up(s, off); if (lane >= off) s += u; }
    if (lane < NB) bsum[lane] = s - v;
}

__global__ void k_scanC(const int* __restrict__ part, const int* __restrict__ bsum,
                        int* __restrict__ offs) {
    const int i = blockIdx.x * SCAN_B + threadIdx.x;
    if (i < N_NODES) offs[i] = part[i] + bsum[blockIdx.x];
    if (i == 0) offs[N_NODES] = ETOT;
}

// ---------------- scatter with LDS cursors: stores exp-weights, no global atomics ----
__global__ void __launch_bounds__(BLD) k_scatter(const int* __restrict__ srcs,
                                                 const int* __restrict__ dsts,
                                                 const float2* __restrict__ sd,
                                                 const float* __restrict__ ec,
                                                 const int* __restrict__ cnt,
                                                 const int* __restrict__ offs,
                                                 unsigned int* __restrict__ csr) {
    __shared__ int cur[NRANGE];
    const int c = blockIdx.x / RSPLIT, r = blockIdx.x % RSPLIT;
    const int nbase = r * NRANGE;
    const int* cslice = cnt + (size_t)c * N_NODES + nbase;
    const int* oslice = offs + nbase;
    for (int i = threadIdx.x; i < NRANGE; i += BLD) cur[i] = oslice[i] + cslice[i];
    __syncthreads();
    const int e0 = c * EPC;
    for (int i = e0 + threadIdx.x; i < e0 + EPC; i += BLD) {
        const int s = srcs[i], d = dsts[i];
        const int dl = d - nbase, sl = s - nbase;
        const bool din = (unsigned)dl < NRANGE;
        const bool sin_ = (unsigned)sl < NRANGE;
        if (!din && !sin_) continue;
        const float e = ec[i];
        const float2 ss = sd[s], dd = sd[d];
        if (din) {   // direction s -> d
            const int pos = atomicAdd(&cur[dl], 1);
            csr[pos] = pack_entry(s, __expf(leaky(ss.x + dd.y + e)));
        }
        if (sin_) {  // direction d -> s
            const int pos = atomicAdd(&cur[sl], 1);
            csr[pos] = pack_entry(d, __expf(leaky(dd.x + ss.y + e)));
        }
    }
}

// ---------------- self-loop entries: last slot of each node's segment ----------
__global__ void k_self(const float2* __restrict__ sd, const int* __restrict__ offs,
                       unsigned int* __restrict__ csr) {
    const int n = blockIdx.x * blockDim.x + threadIdx.x;
    if (n >= N_NODES) return;
    const float2 v = sd[n];
    csr[offs[n + 1] - 1] = pack_entry(n, __expf(leaky(v.x + v.y)));
}

// ---------------- wave-per-node, single pass: acc += w*xt[src]; out = acc/Σw --------
__global__ void k_node(const int* __restrict__ offs, const unsigned int* __restrict__ csr,
                       const __half* __restrict__ xt, float* __restrict__ out) {
    const int node = (blockIdx.x * blockDim.x + threadIdx.x) >> 6;
    const int lane = threadIdx.x & 63;
    if (node >= N_NODES) return;
    const int beg = offs[node], end = offs[node + 1];
    const int jg = lane >> 3;        // 0..7  (8-way edge parallelism)
    const int fc = lane & 7;         // 0..7  (8 halves per lane)
    float acc[8] = {0.f, 0.f, 0.f, 0.f, 0.f, 0.f, 0.f, 0.f};
    float sum = 0.f;
    for (int j = beg + jg; j < end; j += 8) {
        const unsigned int ent = csr[j];
        const int   src = (int)(ent & 0xFFFFu);
        const float w   = __half2float(__ushort_as_half((unsigned short)(ent >> 16)));
        sum += w;
        const uint4 hv = *(const uint4*)(xt + (size_t)src * F + fc * 8);
        const __half2* hp = (const __half2*)&hv;
#pragma unroll
        for (int k = 0; k < 4; ++k) {
            const float2 f = __half22float2(hp[k]);
            acc[2 * k]     += w * f.x;
            acc[2 * k + 1] += w * f.y;
        }
    }
    // reduce across jg (lane bits 3..5)
#pragma unroll
    for (int off = 8; off <= 32; off <<= 1) {
        sum += __shfl_xor(sum, off);
#pragma unroll
        for (int k = 0; k < 8; ++k) acc[k] += __shfl_xor(acc[k], off);
    }
    if (jg == 0) {
        const float inv = 1.0f / sum;
        float4* op = (float4*)(out + (size_t)node * F + fc * 8);
        op[0] = make_float4(acc[0] * inv, acc[1] * inv, acc[2] * inv, acc[3] * inv);
        op[1] = make_float4(acc[4] * inv, acc[5] * inv, acc[6] * inv, acc[7] * inv);
    }
}

extern "C" void kernel_launch(void* const* d_in, const int* in_sizes, int n_in,
                              void* d_out, int out_size, void* d_ws, size_t ws_size,
                              hipStream_t stream) {
    const float* x    = (const float*)d_in[0];
    const int*   ei   = (const int*)d_in[1];
    const float* ea   = (const float*)d_in[2];
    const float* W    = (const float*)d_in[4];
    const float* a    = (const float*)d_in[5];
    float* out = (float*)d_out;

    const int* srcs = ei;             // edge_index[0]
    const int* dsts = ei + N_EDGES;   // edge_index[1]

    char* ws = (char*)d_ws;
    size_t off = 0;
    auto alloc = [&](size_t bytes) { void* p = ws + off; off = (off + bytes + 255) & ~(size_t)255; return p; };
    __half*       xt   = (__half*)alloc((size_t)N_NODES * F * 2);
    float2*       sd   = (float2*)alloc((size_t)N_NODES * 8);
    float*        ec   = (float*)alloc((size_t)N_EDGES * 4);
    int*          cnt  = (int*)alloc((size_t)CCHUNK * N_NODES * 4);   // 12.8 MB
    int*          part = (int*)alloc((size_t)N_NODES * 4);
    int*          bsum = (int*)alloc((size_t)NB * 4);
    int*          offs = (int*)alloc((size_t)(N_NODES + 1) * 4);
    unsigned int* csr  = (unsigned int*)alloc((size_t)ETOT * 4);

    k_xt<<<(N_NODES + 3) / 4, 256, 0, stream>>>(x, W, a, xt, sd);
    k_histA<<<CCHUNK * RSPLIT, BLD, 0, stream>>>(srcs, dsts, ea, a, ec, cnt);
    k_scanA<<<NB, SCAN_B, 0, stream>>>(cnt, part, bsum);
    k_scanB<<<1, 64, 0, stream>>>(bsum);
    k_scanC<<<NB, SCAN_B, 0, stream>>>(part, bsum, offs);
    k_scatter<<<CCHUNK * RSPLIT, BLD, 0, stream>>>(srcs, dsts, sd, ec, cnt, offs, csr);
    k_self<<<(N_NODES + 255) / 256, 256, 0, stream>>>(sd, offs, csr);
    k_node<<<((size_t)N_NODES * 64 + 255) / 256, 256, 0, stream>>>(offs, csr, xt, out);
}